// Round 10
// baseline (116.928 us; speedup 1.0000x reference)
//
#include <hip/hip_runtime.h>
#include <hip/hip_bf16.h>

// out[b,o,n] = sum_{k,c} input[b,c,n] * weight[o,k,c] * score[b,k,n]
// B=8, C_IN=16, C_OUT=16, K=4, N=524288. fp32 in/out.
// MFMA: out[b,:,n] = W'(16x64) . Z(64,n), Z[k*16+c,n] = a[k,n]*x[c,n].
//
// r9 lesson: depth-1 prefetch + in-stage score loads left ~900cy of HBM
// latency on every stage's critical path (all pipes idle, 116us).
// r10: depth-2 pipeline. Triple-buffered x-slab (48KB), STAGE(s+2) issued in
// stage s; scores for s+1 prefetched to VGPRs during stage s; exact FIFO
// counted vmcnt (20 steady / 16 tail) so no loop wait ever blocks on memory.
// Output still transposed through the consumed x-slab (wave-quarter-local)
// into full-line nt dwordx4 stores (keeps WRITE at 262MB, r9 win).

constexpr int B     = 8;
constexpr int C_IN  = 16;
constexpr int C_OUT = 16;
constexpr int KK    = 4;
constexpr long NN   = 524288;            // 2^19
constexpr int W     = 256;               // floats per staged row (1 KB)
constexpr int S     = 8;                 // stages per block
constexpr int BPB   = (int)(NN / (W * S));  // 256 blocks per batch
constexpr int GRID  = B * BPB;           // 2048

typedef short bf16x8 __attribute__((ext_vector_type(8)));
typedef float f32x4  __attribute__((ext_vector_type(4)));

__device__ inline short f2bf(float f) {
    return __builtin_bit_cast(short, __float2bfloat16(f));
}

// global->LDS direct copy, 16 B/lane, zero result VGPRs (tracked by vmcnt).
__device__ inline void gll16(const float* gsrc, float* ldst) {
    __builtin_amdgcn_global_load_lds(
        (const __attribute__((address_space(1))) unsigned int*)gsrc,
        (__attribute__((address_space(3))) unsigned int*)ldst,
        16, 0, 0);
}

__global__ __launch_bounds__(256, 3) void
TransformConv1d_39264591020709_kernel(const float* __restrict__ in,
                                      const float* __restrict__ w,
                                      const float* __restrict__ sc,
                                      float* __restrict__ out) {
    __shared__ float lds[3][C_IN][W];    // 48 KB, triple-buffered x slab

    const int tid  = threadIdx.x;
    const int lane = tid & 63;
    const int wid  = tid >> 6;           // wave 0..3 (owns cols wid*64..+63)
    const int g    = lane >> 4;          // lane group 0..3
    const int col  = lane & 15;

    const int  bi = blockIdx.x;
    const int  b  = bi >> 8;             // / BPB (=256)
    const long n0 = (long)(bi & (BPB - 1)) * (W * S);

    const int ktap = g >> 1;             // score taps {ktap, ktap+2}
    const int c0   = (g & 1) * 8;        // input-channel half

    // A operand (weights): lane holds W'[o=col][kc=g*8+i (+32)] (verified r6-r9).
    bf16x8 w0, w1;
#pragma unroll
    for (int i = 0; i < 8; ++i) {
        w0[i] = f2bf(w[(col * KK + ktap    ) * C_IN + c0 + i]);
        w1[i] = f2bf(w[(col * KK + ktap + 2) * C_IN + c0 + i]);
    }

    const float* inb  = in  + (long)b * C_IN  * NN;
    const float* scb  = sc  + (long)b * KK    * NN;
    float*       outb = out + (long)b * C_OUT * NN;

    // stage: 4 rows per wave, 1 KB (=1 gll instr) per row, into buf s%3.
    auto STAGE = [&](int s) {
        const long noff = n0 + (long)s * W;
#pragma unroll
        for (int j = 0; j < 4; ++j) {
            const int r = wid * 4 + j;
            gll16(inb + (long)r * NN + noff + lane * 4, &lds[s % 3][r][0]);
        }
    };

    // scores for stage s -> 8 VGPRs.
    auto SCORES = [&](int s, float (&a0)[4], float (&a1)[4]) {
        const long nb = n0 + (long)s * W;
#pragma unroll
        for (int u = 0; u < 4; ++u) {
            const int nc = (wid * 4 + u) * 16 + col;
            a0[u] = scb[(long)ktap       * NN + nb + nc];
            a1[u] = scb[(long)(ktap + 2) * NN + nb + nc];
        }
    };

    // ---- prologue: glls_0, glls_1, scores_0; wait glls_0 (12 newer) ----
    STAGE(0);
    STAGE(1);
    float a0c[4], a1c[4];
    SCORES(0, a0c, a1c);
    asm volatile("s_waitcnt vmcnt(12)" ::: "memory");
    __builtin_amdgcn_sched_barrier(0);
    __builtin_amdgcn_s_barrier();
    __builtin_amdgcn_sched_barrier(0);

#pragma unroll
    for (int s = 0; s < S; ++s) {
        const long nb = n0 + (long)s * W;
        float (*X)[W] = lds[s % 3];

        // ---- prefetch: scores for s+1 (VGPR), glls for s+2 (LDS) ----
        float a0n[4], a1n[4];
        if (s + 1 < S) SCORES(s + 1, a0n, a1n);
        __builtin_amdgcn_sched_barrier(0);
        if (s + 2 < S) STAGE(s + 2);
        __builtin_amdgcn_sched_barrier(0);

        // ---- compute 4 tiles from buf s%3; write output back into same slab
        // (wave touches only its own 64-col quarter: no cross-wave hazard) ----
#pragma unroll
        for (int u = 0; u < 4; ++u) {
            const int nt = (wid * 4 + u) * 16;
            float xv[8];
#pragma unroll
            for (int i = 0; i < 8; ++i) xv[i] = X[c0 + i][nt + col];
            bf16x8 z0, z1;
#pragma unroll
            for (int i = 0; i < 8; ++i) {
                z0[i] = f2bf(a0c[u] * xv[i]);
                z1[i] = f2bf(a1c[u] * xv[i]);
            }
            f32x4 acc = {0.f, 0.f, 0.f, 0.f};
            acc = __builtin_amdgcn_mfma_f32_16x16x32_bf16(w0, z0, acc, 0, 0, 0);
            acc = __builtin_amdgcn_mfma_f32_16x16x32_bf16(w1, z1, acc, 0, 0, 0);
#pragma unroll
            for (int r = 0; r < 4; ++r)
                X[g * 4 + r][nt + col] = acc[r];   // D[row=g*4+r][col] -> LDS
        }
        __builtin_amdgcn_sched_barrier(0);

        // ---- read back own quarter (b128), full-line nt dwordx4 stores ----
#pragma unroll
        for (int q = 0; q < 4; ++q) {
            const int row = q * 4 + (lane >> 4);
            const int cq  = wid * 64 + (lane & 15) * 4;
            f32x4 v = *(const f32x4*)&X[row][cq];
            __builtin_nontemporal_store(v,
                (f32x4*)(outb + (long)row * NN + nb + cq));
        }

        // ---- counted wait: retire glls_{s+1}; keep newer prefetch/stores
        // in flight. Newer-than-glls_{s+1}: stores_{s-1}(4) + scores_{s+1}(8)
        // + glls_{s+2}(4 if s+2<S) + stores_s(4) = 20 steady, 16 at s=S-2. ----
        if (s + 1 < S) {
            if (s + 2 < S)
                asm volatile("s_waitcnt vmcnt(20)" ::: "memory");
            else
                asm volatile("s_waitcnt vmcnt(16)" ::: "memory");
            __builtin_amdgcn_sched_barrier(0);
            __builtin_amdgcn_s_barrier();
            __builtin_amdgcn_sched_barrier(0);
        }

        // rotate score registers (static indices; loop fully unrolled)
#pragma unroll
        for (int u = 0; u < 4; ++u) { a0c[u] = a0n[u]; a1c[u] = a1n[u]; }
    }
}

extern "C" void kernel_launch(void* const* d_in, const int* in_sizes, int n_in,
                              void* d_out, int out_size, void* d_ws, size_t ws_size,
                              hipStream_t stream) {
    const float* in = (const float*)d_in[0];   // (B, C_IN, N)
    const float* w  = (const float*)d_in[1];   // (C_OUT, K, C_IN)
    const float* sc = (const float*)d_in[2];   // (B, K, N)
    float* out = (float*)d_out;                // (B, C_OUT, N)

    TransformConv1d_39264591020709_kernel<<<GRID, 256, 0, stream>>>(in, w, sc, out);
}